// Round 20
// baseline (62.242 us; speedup 1.0000x reference)
//
#include <hip/hip_runtime.h>
#include <math.h>

#define W_    128
#define H_    128
#define HW    16384      // 128*128
#define D_    32
#define C_IN  8
#define OC    16
#define NRED  524288.0f  // D_*HW per channel

#define SXS2  37         // staged column stride (pair-dwords), odd
#define SXB2  1998       // 54*37 dwords per staging buffer
#define TILE  2568       // B-tile stride in dwords (512 rows x 5 + 8 zero tail)

typedef __attribute__((ext_vector_type(8))) short bf16x8;
typedef __attribute__((ext_vector_type(4))) float f32x4;

union FragU { uint4 u; bf16x8 h; };

// ws layout (floats):
//   [0,32)       sum[16], sumsq[16]
//   [64,3136)    A-fragments: uint4 per ((pair*3+kd)*64 + lane), pair-packed
//   [8192, +4194304)  y_bf16[o][d][ry][rx] pairs   (if ws_size allows)

__device__ __forceinline__ unsigned bf16rne(float f) {
    unsigned u = __float_as_uint(f);
    return (u + 0x7fffu + ((u >> 16) & 1u)) >> 16;
}

__global__ __launch_bounds__(256) void k_init(const float* __restrict__ wsrc,
                                              float* __restrict__ ws) {
    int t = threadIdx.x;
    if (t < 32) ws[t] = 0.f;
    // Pair-packed A-frag: lane kg<2 -> channel 2p (k=kg*8+i), kg>=2 -> 2p+1
    uint4* af = reinterpret_cast<uint4*>(ws + 64);
    for (int e = t; e < 768; e += 256) {
        int lane = e & 63, pkd = e >> 6;
        int p = pkd / 3, kd = pkd - p * 3;
        int o = lane & 15, kg = lane >> 4;
        int ch = 2 * p + (kg >> 1);
        int jb = (kg & 1) * 8;
        unsigned dw[4];
#pragma unroll
        for (int r2 = 0; r2 < 4; ++r2) {
            int j0 = jb + 2 * r2, j1 = j0 + 1;
            unsigned b0 = (j0 < 9) ? bf16rne(wsrc[(o * 72 + ch * 9 + j0) * 3 + kd]) : 0u;
            unsigned b1 = (j1 < 9) ? bf16rne(wsrc[(o * 72 + ch * 9 + j1) * 3 + kd]) : 0u;
            dw[r2] = b0 | (b1 << 16);
        }
        af[e] = make_uint4(dw[0], dw[1], dw[2], dw[3]);
    }
}

// Staged column pair-dword layout: D[s] = (bf16 slot[s], bf16 slot[s+1]),
// slot[s] = x[z = s-2] (zeros outside z in [0,32)). Gather of taps
// (slot[s0], slot[s0+1]) is a SINGLE b32 read of D[s0].
template <bool YBF>
__global__ __launch_bounds__(512, 4) void k_main(const float* __restrict__ x,
                                                 const float* __restrict__ dp,
                                                 const float* __restrict__ nrm,
                                                 const float* __restrict__ intri,
                                                 const uint4* __restrict__ afr,
                                                 float* __restrict__ out,
                                                 unsigned* __restrict__ ybf,
                                                 float* __restrict__ stats) {
    __shared__ unsigned s_poolU[2 * SXB2];   // pair-dword staging, double-buffered
    __shared__ float s_B[2 * TILE];          // B-tiles; reused as bounce tile later
    __shared__ float s_wgt[144], s_dp0[144], s_inv[144];
    __shared__ float s_red[64];

    int t   = threadIdx.x;
    int bid = blockIdx.x;
    int r_row = bid >> 3;          // 0..127
    int rx0   = (bid & 7) * 16;

    // ---- staging geometry (t < 432): seg 0..2, px 0..17, zq 0..7 ----
    int seg = t / 144;
    int f   = t - seg * 144;
    int spx = f >> 3;
    int zq  = f & 7;
    int srow = min(max(r_row + seg - 1, 0), H_ - 1);
    int scol = min(max(rx0 - 1 + spx, 0), W_ - 1);
    const float* gsrc_raw = x + (srow * W_ + scol);
    int colL = seg * 18 + spx;                 // 0..53
    int sdst = colL * SXS2 + 1 + 4 * zq;       // writes D[1+4zq .. 4+4zq]

    // loads z = 4zq-1 .. 4zq+3 (z=-1 masked to 0)
    float xv[5];
    if (t < 432) {
#pragma unroll
        for (int i = 0; i < 5; ++i) {
            int z = 4 * zq - 1 + i;
            xv[i] = (z >= 0) ? gsrc_raw[(size_t)z * HW] : 0.f;
        }
    }

    if (t < 144) {
        int p = t / 9, j = t - p * 9;
        int jd = j / 3;
        int dy = jd - 1, dx = (j - jd * 3) - 1;
        int cpix = rx0 + p;
        int ry  = min(max(r_row + dy, 0), H_ - 1);
        int rxn = min(max(cpix + dx, 0), W_ - 1);
        int nb  = ry * W_ + rxn;
        float fx = intri[0], cx = intri[2], fy = intri[4], cy = intri[5];
        float nx = nrm[nb], ny = nrm[HW + nb], nz = nrm[2 * HW + nb];
        float pu  = ((float)rxn  - cx) / fx;
        float pv  = ((float)ry   - cy) / fy;
        float puc = ((float)cpix - cx) / fx;
        float pvc = ((float)r_row - cy) / fy;
        float num = nx * puc + ny * pvc + nz;
        float den = nx * pu + ny * pv + nz;
        if (fabsf(den) < 1e-8f)
            den = (den > 0.f) ? 1e-8f : ((den < 0.f) ? -1e-8f : 0.f);
        float w = num / den;
        if (!isfinite(w)) w = 1.0f;
        float d0  = dp[nb];
        float itv = dp[HW + nb] - d0;
        s_wgt[t] = w;
        s_dp0[t] = d0;
        s_inv[t] = 1.0f / itv;
    }
    // zero guard dwords D[0], D[34..36] of all 54 columns, both buffers (2*216)
    if (t < 432) {
        int b  = t / 216;
        int rm = t - b * 216;
        int col = rm >> 2, w4 = rm & 3;
        int off = col * SXS2 + ((w4 == 0) ? 0 : (33 + w4));
        s_poolU[b * SXB2 + off] = 0u;
    }
    // zero both B-tile tails (overflow reads must be finite: r10 lesson)
    if (t < 16) s_B[2560 + (t >> 3) * TILE + (t & 7)] = 0.f;
    __syncthreads();
    if (t < 432) {
        unsigned pd[4];
#pragma unroll
        for (int i = 0; i < 4; ++i) {
            asm("v_cvt_pk_bf16_f32 %0, %1, %2"
                : "=v"(pd[i]) : "v"(xv[i]), "v"(xv[i + 1]));
        }
        s_poolU[sdst + 0] = pd[0];
        s_poolU[sdst + 1] = pd[1];
        s_poolU[sdst + 2] = pd[2];
        s_poolU[sdst + 3] = pd[3];
        if (zq == 7) {   // D[33] = (x31, 0)
            unsigned pe;
            float zz = 0.f;
            asm("v_cvt_pk_bf16_f32 %0, %1, %2" : "=v"(pe) : "v"(xv[4]), "v"(zz));
            s_poolU[colL * SXS2 + 33] = pe;
        }
    }

    // ---- per-thread mapping: px fast, depth slow ----
    int px = t & 15;       // pixel 0..15
    int d  = t >> 4;       // depth 0..31
    float dpv = dp[d * HW + r_row * W_ + rx0 + px];

    int   idq[9];
    float fza[9];
#pragma unroll
    for (int j = 0; j < 9; ++j) {
        int pj = px * 9 + j;
        int jd = j / 3;
        int jx = j - jd * 3;
        float z   = (s_wgt[pj] * dpv - s_dp0[pj]) * s_inv[pj];
        float zc  = fminf(fmaxf(z, -2.0f), 34.0f);   // NaN -> -2 (lands on zeros)
        float z0f = floorf(zc);
        fza[j] = zc - z0f;
        idq[j] = (jd * 18 + px + jx) * SXS2 + 2 + (int)z0f;   // D[s0], s0 in [0,36]
    }
    __syncthreads();   // staging buffer 0 ready

    f32x4 acc0 = {0.f, 0.f, 0.f, 0.f};
    f32x4 acc1 = {0.f, 0.f, 0.f, 0.f};
    f32x4 acc2 = {0.f, 0.f, 0.f, 0.f};
    f32x4 acc3 = {0.f, 0.f, 0.f, 0.f};

    int lane = t & 63;
    int wid  = t >> 6;
    int wb   = wid * 4;            // wave's y depth-tile base
    int grp  = lane >> 4;
    unsigned* sBu = reinterpret_cast<unsigned*>(s_B);
    int wrow = (d * 16 + px) * 5;  // fill write base within tile

    for (int c = 0; c < C_IN; ++c) {
        // prefetch next channel's staging values (strided raw-x; latency hidden)
        if (c < 7 && t < 432) {
            const float* bp = gsrc_raw + (size_t)(c + 1) * (D_ * HW);
#pragma unroll
            for (int i = 0; i < 5; ++i) {
                int z = 4 * zq - 1 + i;
                xv[i] = (z >= 0) ? bp[(size_t)z * HW] : 0.f;
            }
        }
        // ---- fill: 1 pair-dword read per tap-pair, lerp, pack, 5 dwords out ----
        const unsigned* PU = s_poolU + (c & 1) * SXB2;
        float cj[9];
#pragma unroll
        for (int j = 0; j < 9; ++j) {
            unsigned u = PU[idq[j]];
            float a = __uint_as_float(u << 16);
            float b = __uint_as_float(u & 0xffff0000u);
            cj[j] = fmaf(fza[j], b - a, a);
        }
        unsigned dwv[5];
#pragma unroll
        for (int r2 = 0; r2 < 4; ++r2) {
            asm("v_cvt_pk_bf16_f32 %0, %1, %2"
                : "=v"(dwv[r2]) : "v"(cj[2 * r2]), "v"(cj[2 * r2 + 1]));
        }
        {
            float zz = 0.f;
            asm("v_cvt_pk_bf16_f32 %0, %1, %2"
                : "=v"(dwv[4]) : "v"(cj[8]), "v"(zz));
        }
        {
            int wo = wrow + (c & 1) * TILE;
            sBu[wo + 0] = dwv[0];
            sBu[wo + 1] = dwv[1];
            sBu[wo + 2] = dwv[2];
            sBu[wo + 3] = dwv[3];
            sBu[wo + 4] = dwv[4];
        }
        if (c < 7 && t < 432) {
            int ds2 = ((c + 1) & 1) * SXB2;
            unsigned pd[4];
#pragma unroll
            for (int i = 0; i < 4; ++i) {
                asm("v_cvt_pk_bf16_f32 %0, %1, %2"
                    : "=v"(pd[i]) : "v"(xv[i]), "v"(xv[i + 1]));
            }
            s_poolU[ds2 + sdst + 0] = pd[0];
            s_poolU[ds2 + sdst + 1] = pd[1];
            s_poolU[ds2 + sdst + 2] = pd[2];
            s_poolU[ds2 + sdst + 3] = pd[3];
            if (zq == 7) {
                unsigned pe;
                float zz = 0.f;
                asm("v_cvt_pk_bf16_f32 %0, %1, %2" : "=v"(pe) : "v"(xv[4]), "v"(zz));
                s_poolU[ds2 + colL * SXS2 + 33] = pe;
            }
        }
        __syncthreads();   // tile(c&1) ready; staging buf((c+1)&1) ready

        if (c & 1) {
            // ---- MFMA conv for channel pair p = c>>1 (both tiles) ----
            int p = c >> 1;
            FragU a0, a1, a2;
            a0.u = afr[(p * 3 + 0) * 64 + lane];
            a1.u = afr[(p * 3 + 1) * 64 + lane];
            a2.u = afr[(p * 3 + 2) * 64 + lane];
            int boff = ((grp & 1) ? 4 : 0) + ((grp >> 1) ? TILE : 0);
#pragma unroll
            for (int q = 0; q < 6; ++q) {
                int db = wb - 1 + q;
                if (db < 0 || db > 31) continue;   // wave-uniform edge skip
                FragU bf;
                int base = (db * 16 + px) * 5 + boff;
                bf.u.x = sBu[base + 0];
                bf.u.y = sBu[base + 1];
                bf.u.z = sBu[base + 2];
                bf.u.w = sBu[base + 3];
                // dt = q - kd (static); unused B slots finite, zero A k-slots
                if (q - 0 >= 0 && q - 0 < 4)
                    *(q == 0 ? &acc0 : q == 1 ? &acc1 : q == 2 ? &acc2 : &acc3) =
                        __builtin_amdgcn_mfma_f32_16x16x32_bf16(a0.h, bf.h,
                            *(q == 0 ? &acc0 : q == 1 ? &acc1 : q == 2 ? &acc2 : &acc3), 0, 0, 0);
                if (q - 1 >= 0 && q - 1 < 4)
                    *(q == 1 ? &acc0 : q == 2 ? &acc1 : q == 3 ? &acc2 : &acc3) =
                        __builtin_amdgcn_mfma_f32_16x16x32_bf16(a1.h, bf.h,
                            *(q == 1 ? &acc0 : q == 2 ? &acc1 : q == 3 ? &acc2 : &acc3), 0, 0, 0);
                if (q - 2 >= 0 && q - 2 < 4)
                    *(q == 2 ? &acc0 : q == 3 ? &acc1 : q == 4 ? &acc2 : &acc3) =
                        __builtin_amdgcn_mfma_f32_16x16x32_bf16(a2.h, bf.h,
                            *(q == 2 ? &acc0 : q == 3 ? &acc1 : q == 4 ? &acc2 : &acc3), 0, 0, 0);
            }
            __syncthreads();   // tiles consumed; next fill may overwrite
        }
    }

    // ---- store via padded LDS bounce (reuses s_B) + BN partial sums ----
    float* s_b = s_B;            // 2176 floats needed, 5136 available
    float bns[4], bnq[4];
    int o_l = t >> 7;            // read-side o within quad
    int dd  = (t >> 2) & 31;
    int q4  = t & 3;
#pragma unroll
    for (int oo = 0; oo < 4; ++oo) {
        if (grp == oo) {
#pragma unroll
            for (int r2 = 0; r2 < 4; ++r2) {
                s_b[(r2 * 32 + wb + 0) * 17 + px] = acc0[r2];
                s_b[(r2 * 32 + wb + 1) * 17 + px] = acc1[r2];
                s_b[(r2 * 32 + wb + 2) * 17 + px] = acc2[r2];
                s_b[(r2 * 32 + wb + 3) * 17 + px] = acc3[r2];
            }
        }
        __syncthreads();
        const float* brow = &s_b[(o_l * 32 + dd) * 17 + q4 * 4];
        float4 yv;
        yv.x = brow[0]; yv.y = brow[1]; yv.z = brow[2]; yv.w = brow[3];
        int o = oo * 4 + o_l;
        size_t base = (size_t)(o * 32 + dd) * HW + r_row * W_ + rx0 + q4 * 4;
        if (YBF) {
            unsigned dA, dB;
            asm("v_cvt_pk_bf16_f32 %0, %1, %2" : "=v"(dA) : "v"(yv.x), "v"(yv.y));
            asm("v_cvt_pk_bf16_f32 %0, %1, %2" : "=v"(dB) : "v"(yv.z), "v"(yv.w));
            uint2 wv; wv.x = dA; wv.y = dB;
            reinterpret_cast<uint2*>(ybf)[base >> 2] = wv;
        } else {
            *reinterpret_cast<float4*>(out + base) = yv;
        }
        bns[oo] = yv.x + yv.y + yv.z + yv.w;
        bnq[oo] = yv.x * yv.x + yv.y * yv.y + yv.z * yv.z + yv.w * yv.w;
        __syncthreads();
    }

    // wave-reduce each chunk's (sum, sumsq)
#pragma unroll
    for (int oo = 0; oo < 4; ++oo) {
        float s = bns[oo], sq = bnq[oo];
#pragma unroll
        for (int m = 1; m < 64; m <<= 1) {
            s  += __shfl_xor(s, m, 64);
            sq += __shfl_xor(sq, m, 64);
        }
        if ((t & 63) == 0) {
            int w = t >> 6;
            s_red[w * 4 + oo]      = s;
            s_red[32 + w * 4 + oo] = sq;
        }
    }
    __syncthreads();
    if (t < 32) {
        int o  = t & 15;
        int oo = o >> 2, wh = o & 3;
        if (t < 16) {
            float s = s_red[(2 * wh) * 4 + oo] + s_red[(2 * wh + 1) * 4 + oo];
            atomicAdd(&stats[o], s);
        } else {
            float sq = s_red[32 + (2 * wh) * 4 + oo] + s_red[32 + (2 * wh + 1) * 4 + oo];
            atomicAdd(&stats[16 + o], sq);
        }
    }
}

template <bool YBF>
__global__ __launch_bounds__(256) void k_bn(float* __restrict__ out,
                                            const unsigned* __restrict__ ybf,
                                            const float* __restrict__ stats,
                                            const float* __restrict__ gamma,
                                            const float* __restrict__ beta) {
    int i4 = blockIdx.x * 256 + threadIdx.x;   // 2,097,152 groups of 4 elements
    int o  = i4 >> 17;
    float invN = 1.f / NRED;
    float mean = stats[o] * invN;
    float var  = stats[16 + o] * invN - mean * mean;
    float rstd = rsqrtf(var + 1e-5f);
    float a = gamma[o] * rstd;
    float b = beta[o] - mean * a;
    float4 y;
    if (YBF) {
        uint2 v = reinterpret_cast<const uint2*>(ybf)[i4];
        y.x = __uint_as_float(v.x << 16);
        y.y = __uint_as_float(v.x & 0xffff0000u);
        y.z = __uint_as_float(v.y << 16);
        y.w = __uint_as_float(v.y & 0xffff0000u);
    } else {
        y = reinterpret_cast<float4*>(out)[i4];
    }
    y.x = fmaxf(0.f, fmaf(y.x, a, b));
    y.y = fmaxf(0.f, fmaf(y.y, a, b));
    y.z = fmaxf(0.f, fmaf(y.z, a, b));
    y.w = fmaxf(0.f, fmaf(y.w, a, b));
    reinterpret_cast<float4*>(out)[i4] = y;
}

extern "C" void kernel_launch(void* const* d_in, const int* in_sizes, int n_in,
                              void* d_out, int out_size, void* d_ws, size_t ws_size,
                              hipStream_t stream) {
    const float* x     = (const float*)d_in[0];
    const float* dp    = (const float*)d_in[1];
    const float* nrm   = (const float*)d_in[2];
    const float* intri = (const float*)d_in[3];
    const float* wsrc  = (const float*)d_in[4];
    const float* gamma = (const float*)d_in[5];
    const float* beta  = (const float*)d_in[6];
    float* out = (float*)d_out;
    float* ws  = (float*)d_ws;

    bool yb_ok = ws_size >= (size_t)(8192 + 4194304) * 4;
    unsigned* ybf = (unsigned*)(ws + 8192);
    const uint4* afr = (const uint4*)(ws + 64);

    hipLaunchKernelGGL(k_init, dim3(1), dim3(256), 0, stream, wsrc, ws);
    if (yb_ok) {
        hipLaunchKernelGGL(k_main<true>, dim3(1024), dim3(512), 0, stream,
                           x, dp, nrm, intri, afr, out, ybf, ws);
        hipLaunchKernelGGL(k_bn<true>, dim3(8192), dim3(256), 0, stream,
                           out, ybf, ws, gamma, beta);
    } else {
        hipLaunchKernelGGL(k_main<false>, dim3(1024), dim3(512), 0, stream,
                           x, dp, nrm, intri, afr, out, ybf, ws);
        hipLaunchKernelGGL(k_bn<false>, dim3(8192), dim3(256), 0, stream,
                           out, ybf, ws, gamma, beta);
    }
}

// Round 21
// 60.425 us; speedup vs baseline: 1.0301x; 1.0301x over previous
//
#include <hip/hip_runtime.h>
#include <math.h>

#define W_    128
#define H_    128
#define HW    16384      // 128*128
#define D_    32
#define C_IN  8
#define OC    16
#define NRED  524288.0f  // D_*HW per channel

#define SXS2  37         // staged column stride (pair-dwords), odd
#define SXB2  1998       // 54*37 dwords per staging buffer
#define TILE  2568       // B-tile stride in dwords (512 rows x 5 + 8 zero tail)
// raw fallback path
#define SXS   36
#define SXB   1948

typedef __attribute__((ext_vector_type(8))) short bf16x8;
typedef __attribute__((ext_vector_type(4))) float f32x4;

union FragU { uint4 u; bf16x8 h; };

// ws layout (floats):
//   [0,32)       sum[16], sumsq[16]
//   [64,3136)    A-fragments: uint4 per ((pair*3+kd)*64 + lane), pair-packed
//   [8192, +4849664)          xpd pair-dwords [c][pix][37]
//   [8192+4849664, +4194304)  y_bf16[o][d][ry][rx] pairs

__device__ __forceinline__ unsigned bf16rne(float f) {
    unsigned u = __float_as_uint(f);
    return (u + 0x7fffu + ((u >> 16) & 1u)) >> 16;
}

__device__ __forceinline__ void init_ws(int t, const float* __restrict__ wsrc,
                                        float* __restrict__ ws) {
    if (t < 32) ws[t] = 0.f;
    uint4* af = reinterpret_cast<uint4*>(ws + 64);
    for (int e = t; e < 768; e += 256) {
        int lane = e & 63, pkd = e >> 6;
        int p = pkd / 3, kd = pkd - p * 3;
        int o = lane & 15, kg = lane >> 4;
        int ch = 2 * p + (kg >> 1);
        int jb = (kg & 1) * 8;
        unsigned dw[4];
#pragma unroll
        for (int r2 = 0; r2 < 4; ++r2) {
            int j0 = jb + 2 * r2, j1 = j0 + 1;
            unsigned b0 = (j0 < 9) ? bf16rne(wsrc[(o * 72 + ch * 9 + j0) * 3 + kd]) : 0u;
            unsigned b1 = (j1 < 9) ? bf16rne(wsrc[(o * 72 + ch * 9 + j1) * 3 + kd]) : 0u;
            dw[r2] = b0 | (b1 << 16);
        }
        af[e] = make_uint4(dw[0], dw[1], dw[2], dw[3]);
    }
}

__global__ __launch_bounds__(256) void k_init(const float* __restrict__ wsrc,
                                              float* __restrict__ ws) {
    init_ws((int)threadIdx.x, wsrc, ws);
}

// x[c][z][ry][rx] -> xpd[c][ry*128+rx][s]: D[s]=(bf16 x[s-2], bf16 x[s-1]),
// zeros outside z in [0,32). Block 0 also inits ws.
__global__ __launch_bounds__(256) void k_transpose_pd(const float* __restrict__ x,
                                                      unsigned* __restrict__ xpd,
                                                      const float* __restrict__ wsrc,
                                                      float* __restrict__ ws) {
    __shared__ float tile[32 * 132];
    __shared__ unsigned s_D[128 * 37];   // 4736 dwords
    int bid = blockIdx.x;
    int c  = bid >> 7;
    int ry = bid & 127;
    int t  = threadIdx.x;
    if (bid == 0) init_ws(t, wsrc, ws);
    const float* src = x + c * (D_ * HW) + ry * W_;
    for (int k = 0; k < 4; ++k) {
        int e  = t * 4 + k * 1024;
        int z  = e >> 7;
        int rx = e & 127;
        float4 v = *reinterpret_cast<const float4*>(src + z * HW + rx);
        *reinterpret_cast<float4*>(&tile[z * 132 + rx]) = v;
    }
    __syncthreads();
    // thread (rx = t>>1, half = t&1) builds D[s] for s in [19h, 19h+19) (h=1: 18)
    {
        int rx = t >> 1;
        int h  = t & 1;
        int s0 = h * 19;
        int ns = 19 - h;           // 19 or 18
        for (int i = 0; i < ns; ++i) {
            int s = s0 + i;
            int z0 = s - 2, z1 = s - 1;
            float a = (z0 >= 0 && z0 < 32) ? tile[z0 * 132 + rx] : 0.f;
            float b = (z1 >= 0 && z1 < 32) ? tile[z1 * 132 + rx] : 0.f;
            unsigned d;
            asm("v_cvt_pk_bf16_f32 %0, %1, %2" : "=v"(d) : "v"(a), "v"(b));
            s_D[rx * 37 + s] = d;
        }
    }
    __syncthreads();
    // coalesced copy out: 4736 dwords = 1184 uint4
    unsigned* dst = xpd + (size_t)(c * HW + ry * W_) * 37;
    const uint4* sd4 = reinterpret_cast<const uint4*>(s_D);
    uint4* gd4 = reinterpret_cast<uint4*>(dst);
    for (int i = t; i < 1184; i += 256) gd4[i] = sd4[i];
}

// pair-dword staged main kernel (xpd input, ybf output). Gather of taps
// (x[z0], x[z0+1]) is a SINGLE b32 read of D[2+z0].
__global__ __launch_bounds__(512, 4) void k_main_pd(const unsigned* __restrict__ xpd,
                                                    const float* __restrict__ dp,
                                                    const float* __restrict__ nrm,
                                                    const float* __restrict__ intri,
                                                    const uint4* __restrict__ afr,
                                                    unsigned* __restrict__ ybf,
                                                    float* __restrict__ stats) {
    __shared__ unsigned s_poolU[2 * SXB2];   // pair-dword staging, double-buffered
    __shared__ float s_B[2 * TILE];          // B-tiles; reused as bounce tile later
    __shared__ float s_wgt[144], s_dp0[144], s_inv[144];
    __shared__ float s_red[64];

    int t   = threadIdx.x;
    int bid = blockIdx.x;
    int r_row = bid >> 3;          // 0..127
    int rx0   = (bid & 7) * 16;

    // ---- staging geometry (t < 432): seg 0..2, px 0..17, zq 0..7 ----
    int seg = t / 144;
    int f   = t - seg * 144;
    int spx = f >> 3;
    int zq  = f & 7;
    int srow = min(max(r_row + seg - 1, 0), H_ - 1);
    int scol = min(max(rx0 - 1 + spx, 0), W_ - 1);
    const unsigned* gsrcU = xpd + (size_t)(srow * W_ + scol) * 37;
    int colL = seg * 18 + spx;                 // 0..53
    int nld  = (zq == 7) ? 2 : 5;              // dwords this thread stages
    int soff = 5 * zq;                         // 0,5,..,30; zq=7 -> 35,36
    int sdst = colL * SXS2 + soff;

    unsigned pd[5];
    if (t < 432) {
#pragma unroll
        for (int i = 0; i < 5; ++i)
            if (i < nld) pd[i] = gsrcU[soff + i];
    }

    if (t < 144) {
        int p = t / 9, j = t - p * 9;
        int jd = j / 3;
        int dy = jd - 1, dx = (j - jd * 3) - 1;
        int cpix = rx0 + p;
        int ry  = min(max(r_row + dy, 0), H_ - 1);
        int rxn = min(max(cpix + dx, 0), W_ - 1);
        int nb  = ry * W_ + rxn;
        float fx = intri[0], cx = intri[2], fy = intri[4], cy = intri[5];
        float nx = nrm[nb], ny = nrm[HW + nb], nz = nrm[2 * HW + nb];
        float pu  = ((float)rxn  - cx) / fx;
        float pv  = ((float)ry   - cy) / fy;
        float puc = ((float)cpix - cx) / fx;
        float pvc = ((float)r_row - cy) / fy;
        float num = nx * puc + ny * pvc + nz;
        float den = nx * pu + ny * pv + nz;
        if (fabsf(den) < 1e-8f)
            den = (den > 0.f) ? 1e-8f : ((den < 0.f) ? -1e-8f : 0.f);
        float w = num / den;
        if (!isfinite(w)) w = 1.0f;
        float d0  = dp[nb];
        float itv = dp[HW + nb] - d0;
        s_wgt[t] = w;
        s_dp0[t] = d0;
        s_inv[t] = 1.0f / itv;
    }
    // zero both B-tile tails (overflow reads must be finite: r10 lesson)
    if (t < 16) s_B[2560 + (t >> 3) * TILE + (t & 7)] = 0.f;
    __syncthreads();
    if (t < 432) {
#pragma unroll
        for (int i = 0; i < 5; ++i)
            if (i < nld) s_poolU[sdst + i] = pd[i];
    }

    // ---- per-thread mapping: px fast, depth slow ----
    int px = t & 15;       // pixel 0..15
    int d  = t >> 4;       // depth 0..31
    float dpv = dp[d * HW + r_row * W_ + rx0 + px];

    int   idq[9];
    float fza[9];
#pragma unroll
    for (int j = 0; j < 9; ++j) {
        int pj = px * 9 + j;
        int jd = j / 3;
        int jx = j - jd * 3;
        float z   = (s_wgt[pj] * dpv - s_dp0[pj]) * s_inv[pj];
        float zc  = fminf(fmaxf(z, -2.0f), 34.0f);   // NaN -> -2 (lands on zeros)
        float z0f = floorf(zc);
        fza[j] = zc - z0f;
        idq[j] = (jd * 18 + px + jx) * SXS2 + 2 + (int)z0f;   // D[s0], s0 in [0,36]
    }
    __syncthreads();   // staging buffer 0 ready

    f32x4 acc0 = {0.f, 0.f, 0.f, 0.f};
    f32x4 acc1 = {0.f, 0.f, 0.f, 0.f};
    f32x4 acc2 = {0.f, 0.f, 0.f, 0.f};
    f32x4 acc3 = {0.f, 0.f, 0.f, 0.f};

    int lane = t & 63;
    int wid  = t >> 6;
    int wb   = wid * 4;            // wave's y depth-tile base
    int grp  = lane >> 4;
    unsigned* sBu = reinterpret_cast<unsigned*>(s_B);
    int wrow = (d * 16 + px) * 5;  // fill write base within tile

    for (int c = 0; c < C_IN; ++c) {
        // prefetch next channel's staging dwords (coalesced; latency hidden)
        if (c < 7 && t < 432) {
            const unsigned* bp = gsrcU + (size_t)(c + 1) * (HW * 37);
#pragma unroll
            for (int i = 0; i < 5; ++i)
                if (i < nld) pd[i] = bp[soff + i];
        }
        // ---- fill: 1 pair-dword read per tap-pair, lerp, pack, 5 dwords out ----
        const unsigned* PU = s_poolU + (c & 1) * SXB2;
        float cj[9];
#pragma unroll
        for (int j = 0; j < 9; ++j) {
            unsigned u = PU[idq[j]];
            float a = __uint_as_float(u << 16);
            float b = __uint_as_float(u & 0xffff0000u);
            cj[j] = fmaf(fza[j], b - a, a);
        }
        unsigned dwv[5];
#pragma unroll
        for (int r2 = 0; r2 < 4; ++r2) {
            asm("v_cvt_pk_bf16_f32 %0, %1, %2"
                : "=v"(dwv[r2]) : "v"(cj[2 * r2]), "v"(cj[2 * r2 + 1]));
        }
        {
            float zz = 0.f;
            asm("v_cvt_pk_bf16_f32 %0, %1, %2"
                : "=v"(dwv[4]) : "v"(cj[8]), "v"(zz));
        }
        {
            int wo = wrow + (c & 1) * TILE;
            sBu[wo + 0] = dwv[0];
            sBu[wo + 1] = dwv[1];
            sBu[wo + 2] = dwv[2];
            sBu[wo + 3] = dwv[3];
            sBu[wo + 4] = dwv[4];
        }
        if (c < 7 && t < 432) {
            int ds2 = ((c + 1) & 1) * SXB2 + sdst;
#pragma unroll
            for (int i = 0; i < 5; ++i)
                if (i < nld) s_poolU[ds2 + i] = pd[i];
        }
        __syncthreads();   // tile(c&1) ready; staging buf((c+1)&1) ready

        if (c & 1) {
            // ---- MFMA conv for channel pair p = c>>1 (both tiles) ----
            int p = c >> 1;
            FragU a0, a1, a2;
            a0.u = afr[(p * 3 + 0) * 64 + lane];
            a1.u = afr[(p * 3 + 1) * 64 + lane];
            a2.u = afr[(p * 3 + 2) * 64 + lane];
            int boff = ((grp & 1) ? 4 : 0) + ((grp >> 1) ? TILE : 0);
#pragma unroll
            for (int q = 0; q < 6; ++q) {
                int db = wb - 1 + q;
                if (db < 0 || db > 31) continue;   // wave-uniform edge skip
                FragU bf;
                int base = (db * 16 + px) * 5 + boff;
                bf.u.x = sBu[base + 0];
                bf.u.y = sBu[base + 1];
                bf.u.z = sBu[base + 2];
                bf.u.w = sBu[base + 3];
                // dt = q - kd (static); unused B slots finite, zero A k-slots
                if (q - 0 >= 0 && q - 0 < 4)
                    *(q == 0 ? &acc0 : q == 1 ? &acc1 : q == 2 ? &acc2 : &acc3) =
                        __builtin_amdgcn_mfma_f32_16x16x32_bf16(a0.h, bf.h,
                            *(q == 0 ? &acc0 : q == 1 ? &acc1 : q == 2 ? &acc2 : &acc3), 0, 0, 0);
                if (q - 1 >= 0 && q - 1 < 4)
                    *(q == 1 ? &acc0 : q == 2 ? &acc1 : q == 3 ? &acc2 : &acc3) =
                        __builtin_amdgcn_mfma_f32_16x16x32_bf16(a1.h, bf.h,
                            *(q == 1 ? &acc0 : q == 2 ? &acc1 : q == 3 ? &acc2 : &acc3), 0, 0, 0);
                if (q - 2 >= 0 && q - 2 < 4)
                    *(q == 2 ? &acc0 : q == 3 ? &acc1 : q == 4 ? &acc2 : &acc3) =
                        __builtin_amdgcn_mfma_f32_16x16x32_bf16(a2.h, bf.h,
                            *(q == 2 ? &acc0 : q == 3 ? &acc1 : q == 4 ? &acc2 : &acc3), 0, 0, 0);
            }
            __syncthreads();   // tiles consumed; next fill may overwrite
        }
    }

    // ---- store (bf16 y) via padded bounce in s_B + BN partial sums ----
    float* s_b = s_B;            // 2176 floats needed, 5136 available
    float bns[4], bnq[4];
    int o_l = t >> 7;
    int dd  = (t >> 2) & 31;
    int q4  = t & 3;
#pragma unroll
    for (int oo = 0; oo < 4; ++oo) {
        if (grp == oo) {
#pragma unroll
            for (int r2 = 0; r2 < 4; ++r2) {
                s_b[(r2 * 32 + wb + 0) * 17 + px] = acc0[r2];
                s_b[(r2 * 32 + wb + 1) * 17 + px] = acc1[r2];
                s_b[(r2 * 32 + wb + 2) * 17 + px] = acc2[r2];
                s_b[(r2 * 32 + wb + 3) * 17 + px] = acc3[r2];
            }
        }
        __syncthreads();
        const float* brow = &s_b[(o_l * 32 + dd) * 17 + q4 * 4];
        float4 yv;
        yv.x = brow[0]; yv.y = brow[1]; yv.z = brow[2]; yv.w = brow[3];
        int o = oo * 4 + o_l;
        size_t base = (size_t)(o * 32 + dd) * HW + r_row * W_ + rx0 + q4 * 4;
        unsigned dA, dB;
        asm("v_cvt_pk_bf16_f32 %0, %1, %2" : "=v"(dA) : "v"(yv.x), "v"(yv.y));
        asm("v_cvt_pk_bf16_f32 %0, %1, %2" : "=v"(dB) : "v"(yv.z), "v"(yv.w));
        uint2 wv; wv.x = dA; wv.y = dB;
        reinterpret_cast<uint2*>(ybf)[base >> 2] = wv;
        bns[oo] = yv.x + yv.y + yv.z + yv.w;
        bnq[oo] = yv.x * yv.x + yv.y * yv.y + yv.z * yv.z + yv.w * yv.w;
        __syncthreads();
    }

    // wave-reduce each chunk's (sum, sumsq)
#pragma unroll
    for (int oo = 0; oo < 4; ++oo) {
        float s = bns[oo], sq = bnq[oo];
#pragma unroll
        for (int m = 1; m < 64; m <<= 1) {
            s  += __shfl_xor(s, m, 64);
            sq += __shfl_xor(sq, m, 64);
        }
        if ((t & 63) == 0) {
            int w = t >> 6;
            s_red[w * 4 + oo]      = s;
            s_red[32 + w * 4 + oo] = sq;
        }
    }
    __syncthreads();
    if (t < 32) {
        int o  = t & 15;
        int oo = o >> 2, wh = o & 3;
        if (t < 16) {
            float s = s_red[(2 * wh) * 4 + oo] + s_red[(2 * wh + 1) * 4 + oo];
            atomicAdd(&stats[o], s);
        } else {
            float sq = s_red[32 + (2 * wh) * 4 + oo] + s_red[32 + (2 * wh + 1) * 4 + oo];
            atomicAdd(&stats[16 + o], sq);
        }
    }
}

// r18's raw-x kernel, verbatim (fallback when ws too small), f32 out path
__global__ __launch_bounds__(512, 4) void k_main_raw(const float* __restrict__ x,
                                                     const float* __restrict__ dp,
                                                     const float* __restrict__ nrm,
                                                     const float* __restrict__ intri,
                                                     const uint4* __restrict__ afr,
                                                     float* __restrict__ out,
                                                     float* __restrict__ stats) {
    __shared__ float s_pool[2 * SXB];
    __shared__ float s_B[2 * TILE];
    __shared__ float s_wgt[144], s_dp0[144], s_inv[144];
    __shared__ float s_red[64];

    int t   = threadIdx.x;
    int bid = blockIdx.x;
    int r_row = bid >> 3;
    int rx0   = (bid & 7) * 16;

    int seg = t / 144;
    int f   = t - seg * 144;
    int spx = f >> 3;
    int zq  = f & 7;
    int srow = min(max(r_row + seg - 1, 0), H_ - 1);
    int scol = min(max(rx0 - 1 + spx, 0), W_ - 1);
    const float* gsrc_raw = x + (srow * W_ + scol) + (size_t)(zq * 4) * HW;
    int sdst = 4 + (seg * 18 + spx) * SXS + zq * 4;

    float4 sv;
    if (t < 432) {
        sv.x = gsrc_raw[0]; sv.y = gsrc_raw[HW];
        sv.z = gsrc_raw[2 * HW]; sv.w = gsrc_raw[3 * HW];
    }

    if (t < 144) {
        int p = t / 9, j = t - p * 9;
        int jd = j / 3;
        int dy = jd - 1, dx = (j - jd * 3) - 1;
        int cpix = rx0 + p;
        int ry  = min(max(r_row + dy, 0), H_ - 1);
        int rxn = min(max(cpix + dx, 0), W_ - 1);
        int nb  = ry * W_ + rxn;
        float fx = intri[0], cx = intri[2], fy = intri[4], cy = intri[5];
        float nx = nrm[nb], ny = nrm[HW + nb], nz = nrm[2 * HW + nb];
        float pu  = ((float)rxn  - cx) / fx;
        float pv  = ((float)ry   - cy) / fy;
        float puc = ((float)cpix - cx) / fx;
        float pvc = ((float)r_row - cy) / fy;
        float num = nx * puc + ny * pvc + nz;
        float den = nx * pu + ny * pv + nz;
        if (fabsf(den) < 1e-8f)
            den = (den > 0.f) ? 1e-8f : ((den < 0.f) ? -1e-8f : 0.f);
        float w = num / den;
        if (!isfinite(w)) w = 1.0f;
        float d0  = dp[nb];
        float itv = dp[HW + nb] - d0;
        s_wgt[t] = w;
        s_dp0[t] = d0;
        s_inv[t] = 1.0f / itv;
    }
    if (t < 440) {
        int b  = t / 220;
        int rm = t - b * 220;
        int off = (rm < 4) ? rm : (4 + ((rm - 4) >> 2) * SXS + 32 + ((rm - 4) & 3));
        s_pool[b * SXB + off] = 0.f;
    }
    if (t < 16) s_B[2560 + (t >> 3) * TILE + (t & 7)] = 0.f;
    __syncthreads();
    if (t < 432) *reinterpret_cast<float4*>(&s_pool[sdst]) = sv;

    int px = t & 15;
    int d  = t >> 4;
    float dpv = dp[d * HW + r_row * W_ + rx0 + px];

    int   idx[9];
    float fza[9];
#pragma unroll
    for (int j = 0; j < 9; ++j) {
        int pj = px * 9 + j;
        int jd = j / 3;
        int jx = j - jd * 3;
        float z   = (s_wgt[pj] * dpv - s_dp0[pj]) * s_inv[pj];
        float zc  = fminf(fmaxf(z, -2.0f), 34.0f);
        float z0f = floorf(zc);
        fza[j] = zc - z0f;
        idx[j] = (jd * 18 + px + jx) * SXS + (int)z0f;
    }
    __syncthreads();

    f32x4 acc0 = {0.f, 0.f, 0.f, 0.f};
    f32x4 acc1 = {0.f, 0.f, 0.f, 0.f};
    f32x4 acc2 = {0.f, 0.f, 0.f, 0.f};
    f32x4 acc3 = {0.f, 0.f, 0.f, 0.f};

    int lane = t & 63;
    int wid  = t >> 6;
    int wb   = wid * 4;
    int grp  = lane >> 4;
    unsigned* sBu = reinterpret_cast<unsigned*>(s_B);
    int wrow = (d * 16 + px) * 5;

    for (int c = 0; c < C_IN; ++c) {
        if (c < 7 && t < 432) {
            const float* b = gsrc_raw + (size_t)(c + 1) * (D_ * HW);
            sv.x = b[0]; sv.y = b[HW]; sv.z = b[2 * HW]; sv.w = b[3 * HW];
        }
        const float* sxp = &s_pool[(c & 1) * SXB + 4];
        float cj[9];
#pragma unroll
        for (int j = 0; j < 9; ++j) {
            float a = sxp[idx[j]];
            float b = sxp[idx[j] + 1];
            cj[j] = fmaf(fza[j], b - a, a);
        }
        unsigned dwv[5];
#pragma unroll
        for (int r2 = 0; r2 < 4; ++r2) {
            asm("v_cvt_pk_bf16_f32 %0, %1, %2"
                : "=v"(dwv[r2]) : "v"(cj[2 * r2]), "v"(cj[2 * r2 + 1]));
        }
        {
            float zz = 0.f;
            asm("v_cvt_pk_bf16_f32 %0, %1, %2"
                : "=v"(dwv[4]) : "v"(cj[8]), "v"(zz));
        }
        {
            int wo = wrow + (c & 1) * TILE;
            sBu[wo + 0] = dwv[0];
            sBu[wo + 1] = dwv[1];
            sBu[wo + 2] = dwv[2];
            sBu[wo + 3] = dwv[3];
            sBu[wo + 4] = dwv[4];
        }
        if (c < 7 && t < 432) *reinterpret_cast<float4*>(&s_pool[((c + 1) & 1) * SXB + sdst]) = sv;
        __syncthreads();

        if (c & 1) {
            int p = c >> 1;
            FragU a0, a1, a2;
            a0.u = afr[(p * 3 + 0) * 64 + lane];
            a1.u = afr[(p * 3 + 1) * 64 + lane];
            a2.u = afr[(p * 3 + 2) * 64 + lane];
            int boff = ((grp & 1) ? 4 : 0) + ((grp >> 1) ? TILE : 0);
#pragma unroll
            for (int q = 0; q < 6; ++q) {
                int db = wb - 1 + q;
                if (db < 0 || db > 31) continue;
                FragU bf;
                int base = (db * 16 + px) * 5 + boff;
                bf.u.x = sBu[base + 0];
                bf.u.y = sBu[base + 1];
                bf.u.z = sBu[base + 2];
                bf.u.w = sBu[base + 3];
                if (q - 0 >= 0 && q - 0 < 4)
                    *(q == 0 ? &acc0 : q == 1 ? &acc1 : q == 2 ? &acc2 : &acc3) =
                        __builtin_amdgcn_mfma_f32_16x16x32_bf16(a0.h, bf.h,
                            *(q == 0 ? &acc0 : q == 1 ? &acc1 : q == 2 ? &acc2 : &acc3), 0, 0, 0);
                if (q - 1 >= 0 && q - 1 < 4)
                    *(q == 1 ? &acc0 : q == 2 ? &acc1 : q == 3 ? &acc2 : &acc3) =
                        __builtin_amdgcn_mfma_f32_16x16x32_bf16(a1.h, bf.h,
                            *(q == 1 ? &acc0 : q == 2 ? &acc1 : q == 3 ? &acc2 : &acc3), 0, 0, 0);
                if (q - 2 >= 0 && q - 2 < 4)
                    *(q == 2 ? &acc0 : q == 3 ? &acc1 : q == 4 ? &acc2 : &acc3) =
                        __builtin_amdgcn_mfma_f32_16x16x32_bf16(a2.h, bf.h,
                            *(q == 2 ? &acc0 : q == 3 ? &acc1 : q == 4 ? &acc2 : &acc3), 0, 0, 0);
            }
            __syncthreads();
        }
    }

    float* s_b = s_pool;
    float bns[4], bnq[4];
    int o_l = t >> 7;
    int dd  = (t >> 2) & 31;
    int q4  = t & 3;
#pragma unroll
    for (int oo = 0; oo < 4; ++oo) {
        if (grp == oo) {
#pragma unroll
            for (int r2 = 0; r2 < 4; ++r2) {
                s_b[(r2 * 32 + wb + 0) * 17 + px] = acc0[r2];
                s_b[(r2 * 32 + wb + 1) * 17 + px] = acc1[r2];
                s_b[(r2 * 32 + wb + 2) * 17 + px] = acc2[r2];
                s_b[(r2 * 32 + wb + 3) * 17 + px] = acc3[r2];
            }
        }
        __syncthreads();
        const float* brow = &s_b[(o_l * 32 + dd) * 17 + q4 * 4];
        float4 yv;
        yv.x = brow[0]; yv.y = brow[1]; yv.z = brow[2]; yv.w = brow[3];
        int o = oo * 4 + o_l;
        size_t base = (size_t)(o * 32 + dd) * HW + r_row * W_ + rx0 + q4 * 4;
        *reinterpret_cast<float4*>(out + base) = yv;
        bns[oo] = yv.x + yv.y + yv.z + yv.w;
        bnq[oo] = yv.x * yv.x + yv.y * yv.y + yv.z * yv.z + yv.w * yv.w;
        __syncthreads();
    }

#pragma unroll
    for (int oo = 0; oo < 4; ++oo) {
        float s = bns[oo], sq = bnq[oo];
#pragma unroll
        for (int m = 1; m < 64; m <<= 1) {
            s  += __shfl_xor(s, m, 64);
            sq += __shfl_xor(sq, m, 64);
        }
        if ((t & 63) == 0) {
            int w = t >> 6;
            s_red[w * 4 + oo]      = s;
            s_red[32 + w * 4 + oo] = sq;
        }
    }
    __syncthreads();
    if (t < 32) {
        int o  = t & 15;
        int oo = o >> 2, wh = o & 3;
        if (t < 16) {
            float s = s_red[(2 * wh) * 4 + oo] + s_red[(2 * wh + 1) * 4 + oo];
            atomicAdd(&stats[o], s);
        } else {
            float sq = s_red[32 + (2 * wh) * 4 + oo] + s_red[32 + (2 * wh + 1) * 4 + oo];
            atomicAdd(&stats[16 + o], sq);
        }
    }
}

template <bool YBF>
__global__ __launch_bounds__(256) void k_bn(float* __restrict__ out,
                                            const unsigned* __restrict__ ybf,
                                            const float* __restrict__ stats,
                                            const float* __restrict__ gamma,
                                            const float* __restrict__ beta) {
    int i4 = blockIdx.x * 256 + threadIdx.x;
    int o  = i4 >> 17;
    float invN = 1.f / NRED;
    float mean = stats[o] * invN;
    float var  = stats[16 + o] * invN - mean * mean;
    float rstd = rsqrtf(var + 1e-5f);
    float a = gamma[o] * rstd;
    float b = beta[o] - mean * a;
    float4 y;
    if (YBF) {
        uint2 v = reinterpret_cast<const uint2*>(ybf)[i4];
        y.x = __uint_as_float(v.x << 16);
        y.y = __uint_as_float(v.x & 0xffff0000u);
        y.z = __uint_as_float(v.y << 16);
        y.w = __uint_as_float(v.y & 0xffff0000u);
    } else {
        y = reinterpret_cast<float4*>(out)[i4];
    }
    y.x = fmaxf(0.f, fmaf(y.x, a, b));
    y.y = fmaxf(0.f, fmaf(y.y, a, b));
    y.z = fmaxf(0.f, fmaf(y.z, a, b));
    y.w = fmaxf(0.f, fmaf(y.w, a, b));
    reinterpret_cast<float4*>(out)[i4] = y;
}

extern "C" void kernel_launch(void* const* d_in, const int* in_sizes, int n_in,
                              void* d_out, int out_size, void* d_ws, size_t ws_size,
                              hipStream_t stream) {
    const float* x     = (const float*)d_in[0];
    const float* dp    = (const float*)d_in[1];
    const float* nrm   = (const float*)d_in[2];
    const float* intri = (const float*)d_in[3];
    const float* wsrc  = (const float*)d_in[4];
    const float* gamma = (const float*)d_in[5];
    const float* beta  = (const float*)d_in[6];
    float* out = (float*)d_out;
    float* ws  = (float*)d_ws;

    const size_t XPD = (size_t)37 * HW * C_IN;           // 4,849,664 dwords
    bool ok = ws_size >= (size_t)(8192 + XPD + 4194304) * 4;
    unsigned* xpd = (unsigned*)(ws + 8192);
    unsigned* ybf = (unsigned*)(ws + 8192 + XPD);
    const uint4* afr = (const uint4*)(ws + 64);

    if (ok) {
        hipLaunchKernelGGL(k_transpose_pd, dim3(1024), dim3(256), 0, stream,
                           x, xpd, wsrc, ws);
        hipLaunchKernelGGL(k_main_pd, dim3(1024), dim3(512), 0, stream,
                           xpd, dp, nrm, intri, afr, ybf, ws);
        hipLaunchKernelGGL(k_bn<true>, dim3(8192), dim3(256), 0, stream,
                           out, ybf, ws, gamma, beta);
    } else {
        hipLaunchKernelGGL(k_init, dim3(1), dim3(256), 0, stream, wsrc, ws);
        hipLaunchKernelGGL(k_main_raw, dim3(1024), dim3(512), 0, stream,
                           x, dp, nrm, intri, afr, out, ws);
        hipLaunchKernelGGL(k_bn<false>, dim3(8192), dim3(256), 0, stream,
                           out, ybf, ws, gamma, beta);
    }
}

// Round 22
// 57.380 us; speedup vs baseline: 1.0847x; 1.0531x over previous
//
#include <hip/hip_runtime.h>
#include <math.h>

#define W_    128
#define H_    128
#define HW    16384      // 128*128
#define D_    32
#define C_IN  8
#define OC    16
#define NRED  524288.0f  // D_*HW per channel

#define SXS2  37         // staged column stride (pair-dwords), odd
#define SXB2  1998       // 54*37 dwords per staging buffer
#define TILE  2568       // B-tile stride in dwords (512 rows x 5 + 8 zero tail)
// raw fallback path
#define SXS   36
#define SXB   1948

typedef __attribute__((ext_vector_type(8))) short bf16x8;
typedef __attribute__((ext_vector_type(4))) float f32x4;

union FragU { uint4 u; bf16x8 h; };

// ws layout (floats):
//   [0,32)       sum[16], sumsq[16]
//   [64,3136)    A-fragments: uint4 per ((pair*3+kd)*64 + lane), pair-packed
//   [8192, +4849664)          xpd pair-dwords [c][pix][37]
//   [8192+4849664, +4194304)  y_bf16[o][d][ry][rx] pairs

__device__ __forceinline__ unsigned bf16rne(float f) {
    unsigned u = __float_as_uint(f);
    return (u + 0x7fffu + ((u >> 16) & 1u)) >> 16;
}

__device__ __forceinline__ void init_ws(int t, const float* __restrict__ wsrc,
                                        float* __restrict__ ws) {
    if (t < 32) ws[t] = 0.f;
    uint4* af = reinterpret_cast<uint4*>(ws + 64);
    for (int e = t; e < 768; e += 256) {
        int lane = e & 63, pkd = e >> 6;
        int p = pkd / 3, kd = pkd - p * 3;
        int o = lane & 15, kg = lane >> 4;
        int ch = 2 * p + (kg >> 1);
        int jb = (kg & 1) * 8;
        unsigned dw[4];
#pragma unroll
        for (int r2 = 0; r2 < 4; ++r2) {
            int j0 = jb + 2 * r2, j1 = j0 + 1;
            unsigned b0 = (j0 < 9) ? bf16rne(wsrc[(o * 72 + ch * 9 + j0) * 3 + kd]) : 0u;
            unsigned b1 = (j1 < 9) ? bf16rne(wsrc[(o * 72 + ch * 9 + j1) * 3 + kd]) : 0u;
            dw[r2] = b0 | (b1 << 16);
        }
        af[e] = make_uint4(dw[0], dw[1], dw[2], dw[3]);
    }
}

__global__ __launch_bounds__(256) void k_init(const float* __restrict__ wsrc,
                                              float* __restrict__ ws) {
    init_ws((int)threadIdx.x, wsrc, ws);
}

// x[c][z][ry][rx] -> xpd[c][ry*128+rx][s]: D[s]=(bf16 x[s-2], bf16 x[s-1]),
// zeros outside z in [0,32). Block 0 also inits ws.
__global__ __launch_bounds__(256) void k_transpose_pd(const float* __restrict__ x,
                                                      unsigned* __restrict__ xpd,
                                                      const float* __restrict__ wsrc,
                                                      float* __restrict__ ws) {
    __shared__ float tile[32 * 132];
    __shared__ unsigned s_D[128 * 37];   // 4736 dwords
    int bid = blockIdx.x;
    int c  = bid >> 7;
    int ry = bid & 127;
    int t  = threadIdx.x;
    if (bid == 0) init_ws(t, wsrc, ws);
    const float* src = x + c * (D_ * HW) + ry * W_;
    for (int k = 0; k < 4; ++k) {
        int e  = t * 4 + k * 1024;
        int z  = e >> 7;
        int rx = e & 127;
        float4 v = *reinterpret_cast<const float4*>(src + z * HW + rx);
        *reinterpret_cast<float4*>(&tile[z * 132 + rx]) = v;
    }
    __syncthreads();
    {
        int rx = t >> 1;
        int h  = t & 1;
        int s0 = h * 19;
        int ns = 19 - h;
        for (int i = 0; i < ns; ++i) {
            int s = s0 + i;
            int z0 = s - 2, z1 = s - 1;
            float a = (z0 >= 0 && z0 < 32) ? tile[z0 * 132 + rx] : 0.f;
            float b = (z1 >= 0 && z1 < 32) ? tile[z1 * 132 + rx] : 0.f;
            unsigned d;
            asm("v_cvt_pk_bf16_f32 %0, %1, %2" : "=v"(d) : "v"(a), "v"(b));
            s_D[rx * 37 + s] = d;
        }
    }
    __syncthreads();
    unsigned* dst = xpd + (size_t)(c * HW + ry * W_) * 37;
    const uint4* sd4 = reinterpret_cast<const uint4*>(s_D);
    uint4* gd4 = reinterpret_cast<uint4*>(dst);
    for (int i = t; i < 1184; i += 256) gd4[i] = sd4[i];
}

// pair-dword staged main kernel: gather = 1 b32 read per tap-pair; direct
// bf16 stores (no bounce); BN stats from accumulators (r15-validated block).
__global__ __launch_bounds__(512, 4) void k_main_pd(const unsigned* __restrict__ xpd,
                                                    const float* __restrict__ dp,
                                                    const float* __restrict__ nrm,
                                                    const float* __restrict__ intri,
                                                    const uint4* __restrict__ afr,
                                                    unsigned* __restrict__ ybf,
                                                    float* __restrict__ stats) {
    __shared__ unsigned s_poolU[2 * SXB2];   // pair-dword staging, double-buffered
    __shared__ float s_B[2 * TILE];          // B-tiles
    __shared__ float s_wgt[144], s_dp0[144], s_inv[144];
    __shared__ float s_red[256];

    int t   = threadIdx.x;
    int bid = blockIdx.x;
    int r_row = bid >> 3;          // 0..127
    int rx0   = (bid & 7) * 16;

    // ---- staging geometry (t < 432): seg 0..2, px 0..17, zq 0..7 ----
    int seg = t / 144;
    int f   = t - seg * 144;
    int spx = f >> 3;
    int zq  = f & 7;
    int srow = min(max(r_row + seg - 1, 0), H_ - 1);
    int scol = min(max(rx0 - 1 + spx, 0), W_ - 1);
    const unsigned* gsrcU = xpd + (size_t)(srow * W_ + scol) * 37;
    int colL = seg * 18 + spx;
    int nld  = (zq == 7) ? 2 : 5;
    int soff = 5 * zq;
    int sdst = colL * SXS2 + soff;

    unsigned pd[5];
    if (t < 432) {
#pragma unroll
        for (int i = 0; i < 5; ++i)
            if (i < nld) pd[i] = gsrcU[soff + i];
    }

    if (t < 144) {
        int p = t / 9, j = t - p * 9;
        int jd = j / 3;
        int dy = jd - 1, dx = (j - jd * 3) - 1;
        int cpix = rx0 + p;
        int ry  = min(max(r_row + dy, 0), H_ - 1);
        int rxn = min(max(cpix + dx, 0), W_ - 1);
        int nb  = ry * W_ + rxn;
        float fx = intri[0], cx = intri[2], fy = intri[4], cy = intri[5];
        float nx = nrm[nb], ny = nrm[HW + nb], nz = nrm[2 * HW + nb];
        float pu  = ((float)rxn  - cx) / fx;
        float pv  = ((float)ry   - cy) / fy;
        float puc = ((float)cpix - cx) / fx;
        float pvc = ((float)r_row - cy) / fy;
        float num = nx * puc + ny * pvc + nz;
        float den = nx * pu + ny * pv + nz;
        if (fabsf(den) < 1e-8f)
            den = (den > 0.f) ? 1e-8f : ((den < 0.f) ? -1e-8f : 0.f);
        float w = num / den;
        if (!isfinite(w)) w = 1.0f;
        float d0  = dp[nb];
        float itv = dp[HW + nb] - d0;
        s_wgt[t] = w;
        s_dp0[t] = d0;
        s_inv[t] = 1.0f / itv;
    }
    // zero both B-tile tails (overflow reads must be finite: r10 lesson)
    if (t < 16) s_B[2560 + (t >> 3) * TILE + (t & 7)] = 0.f;
    __syncthreads();
    if (t < 432) {
#pragma unroll
        for (int i = 0; i < 5; ++i)
            if (i < nld) s_poolU[sdst + i] = pd[i];
    }

    // ---- per-thread mapping: px fast, depth slow ----
    int px = t & 15;
    int d  = t >> 4;
    float dpv = dp[d * HW + r_row * W_ + rx0 + px];

    int   idq[9];
    float fza[9];
#pragma unroll
    for (int j = 0; j < 9; ++j) {
        int pj = px * 9 + j;
        int jd = j / 3;
        int jx = j - jd * 3;
        float z   = (s_wgt[pj] * dpv - s_dp0[pj]) * s_inv[pj];
        float zc  = fminf(fmaxf(z, -2.0f), 34.0f);   // NaN -> -2 (lands on zeros)
        float z0f = floorf(zc);
        fza[j] = zc - z0f;
        idq[j] = (jd * 18 + px + jx) * SXS2 + 2 + (int)z0f;
    }
    __syncthreads();   // staging buffer 0 ready

    f32x4 acc0 = {0.f, 0.f, 0.f, 0.f};
    f32x4 acc1 = {0.f, 0.f, 0.f, 0.f};
    f32x4 acc2 = {0.f, 0.f, 0.f, 0.f};
    f32x4 acc3 = {0.f, 0.f, 0.f, 0.f};

    int lane = t & 63;
    int wid  = t >> 6;
    int wb   = wid * 4;
    int grp  = lane >> 4;
    unsigned* sBu = reinterpret_cast<unsigned*>(s_B);
    int wrow = (d * 16 + px) * 5;

    for (int c = 0; c < C_IN; ++c) {
        if (c < 7 && t < 432) {
            const unsigned* bp = gsrcU + (size_t)(c + 1) * (HW * 37);
#pragma unroll
            for (int i = 0; i < 5; ++i)
                if (i < nld) pd[i] = bp[soff + i];
        }
        const unsigned* PU = s_poolU + (c & 1) * SXB2;
        float cj[9];
#pragma unroll
        for (int j = 0; j < 9; ++j) {
            unsigned u = PU[idq[j]];
            float a = __uint_as_float(u << 16);
            float b = __uint_as_float(u & 0xffff0000u);
            cj[j] = fmaf(fza[j], b - a, a);
        }
        unsigned dwv[5];
#pragma unroll
        for (int r2 = 0; r2 < 4; ++r2) {
            asm("v_cvt_pk_bf16_f32 %0, %1, %2"
                : "=v"(dwv[r2]) : "v"(cj[2 * r2]), "v"(cj[2 * r2 + 1]));
        }
        {
            float zz = 0.f;
            asm("v_cvt_pk_bf16_f32 %0, %1, %2"
                : "=v"(dwv[4]) : "v"(cj[8]), "v"(zz));
        }
        {
            int wo = wrow + (c & 1) * TILE;
            sBu[wo + 0] = dwv[0];
            sBu[wo + 1] = dwv[1];
            sBu[wo + 2] = dwv[2];
            sBu[wo + 3] = dwv[3];
            sBu[wo + 4] = dwv[4];
        }
        if (c < 7 && t < 432) {
            int ds2 = ((c + 1) & 1) * SXB2 + sdst;
#pragma unroll
            for (int i = 0; i < 5; ++i)
                if (i < nld) s_poolU[ds2 + i] = pd[i];
        }
        __syncthreads();

        if (c & 1) {
            int p = c >> 1;
            FragU a0, a1, a2;
            a0.u = afr[(p * 3 + 0) * 64 + lane];
            a1.u = afr[(p * 3 + 1) * 64 + lane];
            a2.u = afr[(p * 3 + 2) * 64 + lane];
            int boff = ((grp & 1) ? 4 : 0) + ((grp >> 1) ? TILE : 0);
#pragma unroll
            for (int q = 0; q < 6; ++q) {
                int db = wb - 1 + q;
                if (db < 0 || db > 31) continue;
                FragU bf;
                int base = (db * 16 + px) * 5 + boff;
                bf.u.x = sBu[base + 0];
                bf.u.y = sBu[base + 1];
                bf.u.z = sBu[base + 2];
                bf.u.w = sBu[base + 3];
                if (q - 0 >= 0 && q - 0 < 4)
                    *(q == 0 ? &acc0 : q == 1 ? &acc1 : q == 2 ? &acc2 : &acc3) =
                        __builtin_amdgcn_mfma_f32_16x16x32_bf16(a0.h, bf.h,
                            *(q == 0 ? &acc0 : q == 1 ? &acc1 : q == 2 ? &acc2 : &acc3), 0, 0, 0);
                if (q - 1 >= 0 && q - 1 < 4)
                    *(q == 1 ? &acc0 : q == 2 ? &acc1 : q == 3 ? &acc2 : &acc3) =
                        __builtin_amdgcn_mfma_f32_16x16x32_bf16(a1.h, bf.h,
                            *(q == 1 ? &acc0 : q == 2 ? &acc1 : q == 3 ? &acc2 : &acc3), 0, 0, 0);
                if (q - 2 >= 0 && q - 2 < 4)
                    *(q == 2 ? &acc0 : q == 3 ? &acc1 : q == 4 ? &acc2 : &acc3) =
                        __builtin_amdgcn_mfma_f32_16x16x32_bf16(a2.h, bf.h,
                            *(q == 2 ? &acc0 : q == 3 ? &acc1 : q == 4 ? &acc2 : &acc3), 0, 0, 0);
            }
            __syncthreads();
        }
    }

    // ---- BN stats from accumulators (r15-validated): shfl over 16 px lanes ----
    {
        float sA[4], qA[4];
#pragma unroll
        for (int r2 = 0; r2 < 4; ++r2) {
            sA[r2] = acc0[r2] + acc1[r2] + acc2[r2] + acc3[r2];
            qA[r2] = acc0[r2] * acc0[r2] + acc1[r2] * acc1[r2]
                   + acc2[r2] * acc2[r2] + acc3[r2] * acc3[r2];
#pragma unroll
            for (int m = 1; m < 16; m <<= 1) {
                sA[r2] += __shfl_xor(sA[r2], m, 16);
                qA[r2] += __shfl_xor(qA[r2], m, 16);
            }
        }
        if ((lane & 15) == 0) {
            int base = wid * 16 + grp * 4;
#pragma unroll
            for (int r2 = 0; r2 < 4; ++r2) {
                s_red[base + r2]       = sA[r2];
                s_red[128 + base + r2] = qA[r2];
            }
        }
    }
    __syncthreads();
    if (t < 32) {
        int o = t & 15;
        float s = 0.f;
        if (t < 16) {
            for (int w = 0; w < 8; ++w) s += s_red[w * 16 + o];
            atomicAdd(&stats[o], s);
        } else {
            for (int w = 0; w < 8; ++w) s += s_red[128 + w * 16 + o];
            atomicAdd(&stats[16 + o], s);
        }
    }

    // ---- direct bf16 stores: lane holds y[o=grp*4+r2][d=wb+dt][px] ----
    // Wave-store covers 4 fully-written 32B segments (one per grp's o-plane).
    unsigned short* yb16 = reinterpret_cast<unsigned short*>(ybf);
    size_t pbase = (size_t)r_row * W_ + rx0 + px;
    float zz = 0.f;
#pragma unroll
    for (int r2 = 0; r2 < 4; ++r2) {
        int o = grp * 4 + r2;
        size_t ob = (size_t)o * (D_ * HW) + pbase;
        unsigned s0, s1, s2, s3;
        asm("v_cvt_pk_bf16_f32 %0, %1, %2" : "=v"(s0) : "v"(acc0[r2]), "v"(zz));
        asm("v_cvt_pk_bf16_f32 %0, %1, %2" : "=v"(s1) : "v"(acc1[r2]), "v"(zz));
        asm("v_cvt_pk_bf16_f32 %0, %1, %2" : "=v"(s2) : "v"(acc2[r2]), "v"(zz));
        asm("v_cvt_pk_bf16_f32 %0, %1, %2" : "=v"(s3) : "v"(acc3[r2]), "v"(zz));
        yb16[ob + (size_t)(wb + 0) * HW] = (unsigned short)s0;
        yb16[ob + (size_t)(wb + 1) * HW] = (unsigned short)s1;
        yb16[ob + (size_t)(wb + 2) * HW] = (unsigned short)s2;
        yb16[ob + (size_t)(wb + 3) * HW] = (unsigned short)s3;
    }
}

// r18's raw-x kernel, verbatim (fallback when ws too small), f32 out path
__global__ __launch_bounds__(512, 4) void k_main_raw(const float* __restrict__ x,
                                                     const float* __restrict__ dp,
                                                     const float* __restrict__ nrm,
                                                     const float* __restrict__ intri,
                                                     const uint4* __restrict__ afr,
                                                     float* __restrict__ out,
                                                     float* __restrict__ stats) {
    __shared__ float s_pool[2 * SXB];
    __shared__ float s_B[2 * TILE];
    __shared__ float s_wgt[144], s_dp0[144], s_inv[144];
    __shared__ float s_red[64];

    int t   = threadIdx.x;
    int bid = blockIdx.x;
    int r_row = bid >> 3;
    int rx0   = (bid & 7) * 16;

    int seg = t / 144;
    int f   = t - seg * 144;
    int spx = f >> 3;
    int zq  = f & 7;
    int srow = min(max(r_row + seg - 1, 0), H_ - 1);
    int scol = min(max(rx0 - 1 + spx, 0), W_ - 1);
    const float* gsrc_raw = x + (srow * W_ + scol) + (size_t)(zq * 4) * HW;
    int sdst = 4 + (seg * 18 + spx) * SXS + zq * 4;

    float4 sv;
    if (t < 432) {
        sv.x = gsrc_raw[0]; sv.y = gsrc_raw[HW];
        sv.z = gsrc_raw[2 * HW]; sv.w = gsrc_raw[3 * HW];
    }

    if (t < 144) {
        int p = t / 9, j = t - p * 9;
        int jd = j / 3;
        int dy = jd - 1, dx = (j - jd * 3) - 1;
        int cpix = rx0 + p;
        int ry  = min(max(r_row + dy, 0), H_ - 1);
        int rxn = min(max(cpix + dx, 0), W_ - 1);
        int nb  = ry * W_ + rxn;
        float fx = intri[0], cx = intri[2], fy = intri[4], cy = intri[5];
        float nx = nrm[nb], ny = nrm[HW + nb], nz = nrm[2 * HW + nb];
        float pu  = ((float)rxn  - cx) / fx;
        float pv  = ((float)ry   - cy) / fy;
        float puc = ((float)cpix - cx) / fx;
        float pvc = ((float)r_row - cy) / fy;
        float num = nx * puc + ny * pvc + nz;
        float den = nx * pu + ny * pv + nz;
        if (fabsf(den) < 1e-8f)
            den = (den > 0.f) ? 1e-8f : ((den < 0.f) ? -1e-8f : 0.f);
        float w = num / den;
        if (!isfinite(w)) w = 1.0f;
        float d0  = dp[nb];
        float itv = dp[HW + nb] - d0;
        s_wgt[t] = w;
        s_dp0[t] = d0;
        s_inv[t] = 1.0f / itv;
    }
    if (t < 440) {
        int b  = t / 220;
        int rm = t - b * 220;
        int off = (rm < 4) ? rm : (4 + ((rm - 4) >> 2) * SXS + 32 + ((rm - 4) & 3));
        s_pool[b * SXB + off] = 0.f;
    }
    if (t < 16) s_B[2560 + (t >> 3) * TILE + (t & 7)] = 0.f;
    __syncthreads();
    if (t < 432) *reinterpret_cast<float4*>(&s_pool[sdst]) = sv;

    int px = t & 15;
    int d  = t >> 4;
    float dpv = dp[d * HW + r_row * W_ + rx0 + px];

    int   idx[9];
    float fza[9];
#pragma unroll
    for (int j = 0; j < 9; ++j) {
        int pj = px * 9 + j;
        int jd = j / 3;
        int jx = j - jd * 3;
        float z   = (s_wgt[pj] * dpv - s_dp0[pj]) * s_inv[pj];
        float zc  = fminf(fmaxf(z, -2.0f), 34.0f);
        float z0f = floorf(zc);
        fza[j] = zc - z0f;
        idx[j] = (jd * 18 + px + jx) * SXS + (int)z0f;
    }
    __syncthreads();

    f32x4 acc0 = {0.f, 0.f, 0.f, 0.f};
    f32x4 acc1 = {0.f, 0.f, 0.f, 0.f};
    f32x4 acc2 = {0.f, 0.f, 0.f, 0.f};
    f32x4 acc3 = {0.f, 0.f, 0.f, 0.f};

    int lane = t & 63;
    int wid  = t >> 6;
    int wb   = wid * 4;
    int grp  = lane >> 4;
    unsigned* sBu = reinterpret_cast<unsigned*>(s_B);
    int wrow = (d * 16 + px) * 5;

    for (int c = 0; c < C_IN; ++c) {
        if (c < 7 && t < 432) {
            const float* b = gsrc_raw + (size_t)(c + 1) * (D_ * HW);
            sv.x = b[0]; sv.y = b[HW]; sv.z = b[2 * HW]; sv.w = b[3 * HW];
        }
        const float* sxp = &s_pool[(c & 1) * SXB + 4];
        float cj[9];
#pragma unroll
        for (int j = 0; j < 9; ++j) {
            float a = sxp[idx[j]];
            float b = sxp[idx[j] + 1];
            cj[j] = fmaf(fza[j], b - a, a);
        }
        unsigned dwv[5];
#pragma unroll
        for (int r2 = 0; r2 < 4; ++r2) {
            asm("v_cvt_pk_bf16_f32 %0, %1, %2"
                : "=v"(dwv[r2]) : "v"(cj[2 * r2]), "v"(cj[2 * r2 + 1]));
        }
        {
            float zz = 0.f;
            asm("v_cvt_pk_bf16_f32 %0, %1, %2"
                : "=v"(dwv[4]) : "v"(cj[8]), "v"(zz));
        }
        {
            int wo = wrow + (c & 1) * TILE;
            sBu[wo + 0] = dwv[0];
            sBu[wo + 1] = dwv[1];
            sBu[wo + 2] = dwv[2];
            sBu[wo + 3] = dwv[3];
            sBu[wo + 4] = dwv[4];
        }
        if (c < 7 && t < 432) *reinterpret_cast<float4*>(&s_pool[((c + 1) & 1) * SXB + sdst]) = sv;
        __syncthreads();

        if (c & 1) {
            int p = c >> 1;
            FragU a0, a1, a2;
            a0.u = afr[(p * 3 + 0) * 64 + lane];
            a1.u = afr[(p * 3 + 1) * 64 + lane];
            a2.u = afr[(p * 3 + 2) * 64 + lane];
            int boff = ((grp & 1) ? 4 : 0) + ((grp >> 1) ? TILE : 0);
#pragma unroll
            for (int q = 0; q < 6; ++q) {
                int db = wb - 1 + q;
                if (db < 0 || db > 31) continue;
                FragU bf;
                int base = (db * 16 + px) * 5 + boff;
                bf.u.x = sBu[base + 0];
                bf.u.y = sBu[base + 1];
                bf.u.z = sBu[base + 2];
                bf.u.w = sBu[base + 3];
                if (q - 0 >= 0 && q - 0 < 4)
                    *(q == 0 ? &acc0 : q == 1 ? &acc1 : q == 2 ? &acc2 : &acc3) =
                        __builtin_amdgcn_mfma_f32_16x16x32_bf16(a0.h, bf.h,
                            *(q == 0 ? &acc0 : q == 1 ? &acc1 : q == 2 ? &acc2 : &acc3), 0, 0, 0);
                if (q - 1 >= 0 && q - 1 < 4)
                    *(q == 1 ? &acc0 : q == 2 ? &acc1 : q == 3 ? &acc2 : &acc3) =
                        __builtin_amdgcn_mfma_f32_16x16x32_bf16(a1.h, bf.h,
                            *(q == 1 ? &acc0 : q == 2 ? &acc1 : q == 3 ? &acc2 : &acc3), 0, 0, 0);
                if (q - 2 >= 0 && q - 2 < 4)
                    *(q == 2 ? &acc0 : q == 3 ? &acc1 : q == 4 ? &acc2 : &acc3) =
                        __builtin_amdgcn_mfma_f32_16x16x32_bf16(a2.h, bf.h,
                            *(q == 2 ? &acc0 : q == 3 ? &acc1 : q == 4 ? &acc2 : &acc3), 0, 0, 0);
            }
            __syncthreads();
        }
    }

    float* s_b = s_pool;
    float bns[4], bnq[4];
    int o_l = t >> 7;
    int dd  = (t >> 2) & 31;
    int q4  = t & 3;
#pragma unroll
    for (int oo = 0; oo < 4; ++oo) {
        if (grp == oo) {
#pragma unroll
            for (int r2 = 0; r2 < 4; ++r2) {
                s_b[(r2 * 32 + wb + 0) * 17 + px] = acc0[r2];
                s_b[(r2 * 32 + wb + 1) * 17 + px] = acc1[r2];
                s_b[(r2 * 32 + wb + 2) * 17 + px] = acc2[r2];
                s_b[(r2 * 32 + wb + 3) * 17 + px] = acc3[r2];
            }
        }
        __syncthreads();
        const float* brow = &s_b[(o_l * 32 + dd) * 17 + q4 * 4];
        float4 yv;
        yv.x = brow[0]; yv.y = brow[1]; yv.z = brow[2]; yv.w = brow[3];
        int o = oo * 4 + o_l;
        size_t base = (size_t)(o * 32 + dd) * HW + r_row * W_ + rx0 + q4 * 4;
        *reinterpret_cast<float4*>(out + base) = yv;
        bns[oo] = yv.x + yv.y + yv.z + yv.w;
        bnq[oo] = yv.x * yv.x + yv.y * yv.y + yv.z * yv.z + yv.w * yv.w;
        __syncthreads();
    }

#pragma unroll
    for (int oo = 0; oo < 4; ++oo) {
        float s = bns[oo], sq = bnq[oo];
#pragma unroll
        for (int m = 1; m < 64; m <<= 1) {
            s  += __shfl_xor(s, m, 64);
            sq += __shfl_xor(sq, m, 64);
        }
        if ((t & 63) == 0) {
            int w = t >> 6;
            s_red[w * 4 + oo]      = s;
            s_red[32 + w * 4 + oo] = sq;
        }
    }
    __syncthreads();
    if (t < 32) {
        int o  = t & 15;
        int oo = o >> 2, wh = o & 3;
        if (t < 16) {
            float s = s_red[(2 * wh) * 4 + oo] + s_red[(2 * wh + 1) * 4 + oo];
            atomicAdd(&stats[o], s);
        } else {
            float sq = s_red[32 + (2 * wh) * 4 + oo] + s_red[32 + (2 * wh + 1) * 4 + oo];
            atomicAdd(&stats[16 + o], sq);
        }
    }
}

template <bool YBF>
__global__ __launch_bounds__(256) void k_bn(float* __restrict__ out,
                                            const unsigned* __restrict__ ybf,
                                            const float* __restrict__ stats,
                                            const float* __restrict__ gamma,
                                            const float* __restrict__ beta) {
    int i4 = blockIdx.x * 256 + threadIdx.x;
    int o  = i4 >> 17;
    float invN = 1.f / NRED;
    float mean = stats[o] * invN;
    float var  = stats[16 + o] * invN - mean * mean;
    float rstd = rsqrtf(var + 1e-5f);
    float a = gamma[o] * rstd;
    float b = beta[o] - mean * a;
    float4 y;
    if (YBF) {
        uint2 v = reinterpret_cast<const uint2*>(ybf)[i4];
        y.x = __uint_as_float(v.x << 16);
        y.y = __uint_as_float(v.x & 0xffff0000u);
        y.z = __uint_as_float(v.y << 16);
        y.w = __uint_as_float(v.y & 0xffff0000u);
    } else {
        y = reinterpret_cast<float4*>(out)[i4];
    }
    y.x = fmaxf(0.f, fmaf(y.x, a, b));
    y.y = fmaxf(0.f, fmaf(y.y, a, b));
    y.z = fmaxf(0.f, fmaf(y.z, a, b));
    y.w = fmaxf(0.f, fmaf(y.w, a, b));
    reinterpret_cast<float4*>(out)[i4] = y;
}

extern "C" void kernel_launch(void* const* d_in, const int* in_sizes, int n_in,
                              void* d_out, int out_size, void* d_ws, size_t ws_size,
                              hipStream_t stream) {
    const float* x     = (const float*)d_in[0];
    const float* dp    = (const float*)d_in[1];
    const float* nrm   = (const float*)d_in[2];
    const float* intri = (const float*)d_in[3];
    const float* wsrc  = (const float*)d_in[4];
    const float* gamma = (const float*)d_in[5];
    const float* beta  = (const float*)d_in[6];
    float* out = (float*)d_out;
    float* ws  = (float*)d_ws;

    const size_t XPD = (size_t)37 * HW * C_IN;           // 4,849,664 dwords
    bool ok = ws_size >= (size_t)(8192 + XPD + 4194304) * 4;
    unsigned* xpd = (unsigned*)(ws + 8192);
    unsigned* ybf = (unsigned*)(ws + 8192 + XPD);
    const uint4* afr = (const uint4*)(ws + 64);

    if (ok) {
        hipLaunchKernelGGL(k_transpose_pd, dim3(1024), dim3(256), 0, stream,
                           x, xpd, wsrc, ws);
        hipLaunchKernelGGL(k_main_pd, dim3(1024), dim3(512), 0, stream,
                           xpd, dp, nrm, intri, afr, ybf, ws);
        hipLaunchKernelGGL(k_bn<true>, dim3(8192), dim3(256), 0, stream,
                           out, ybf, ws, gamma, beta);
    } else {
        hipLaunchKernelGGL(k_init, dim3(1), dim3(256), 0, stream, wsrc, ws);
        hipLaunchKernelGGL(k_main_raw, dim3(1024), dim3(512), 0, stream,
                           x, dp, nrm, intri, afr, out, ws);
        hipLaunchKernelGGL(k_bn<false>, dim3(8192), dim3(256), 0, stream,
                           out, ybf, ws, gamma, beta);
    }
}